// Round 1
// baseline (709.516 us; speedup 1.0000x reference)
//
#include <hip/hip_runtime.h>

#define N_NODES 25
#define DIMD    128
#define HID     64
#define KNN     4
#define RAD     2.5f

__global__ __launch_bounds__(256) void ig_kernel(
    const float* __restrict__ emb,      // [BT, 25, 128]
    const float* __restrict__ bboxes,   // [BT, 25, 4]
    const int*   __restrict__ pmask,    // [BT, 25]
    const float* __restrict__ ew1,      // [259, 64]
    const float* __restrict__ eb1,      // [64]
    const float* __restrict__ ew2,      // [64, 128]
    const float* __restrict__ eb2,      // [128]
    const float* __restrict__ nw1,      // [256, 64]
    const float* __restrict__ nb1,      // [64]
    const float* __restrict__ nw2,      // [64, 128]
    const float* __restrict__ nb2,      // [128]
    const float* __restrict__ lng,      // [128]
    const float* __restrict__ lnb,      // [128]
    float* __restrict__ out)            // [BT, 25, 128]
{
    const int node = blockIdx.x;          // 0 .. BT*25-1
    const int bt   = node / N_NODES;
    const int i    = node - bt * N_NODES;
    const int t    = threadIdx.x;

    __shared__ float s_cx[N_NODES], s_cy[N_NODES];
    __shared__ int   s_m[N_NODES];
    __shared__ float s_dxn[N_NODES], s_dyn[N_NODES], s_dn[N_NODES];
    __shared__ float s_xi[DIMD];
    __shared__ float s_xj[KNN][DIMD];
    __shared__ int   s_idx[KNN];
    __shared__ float s_val[KNN];          // nbr_valid as 0/1 float
    __shared__ float s_e[KNN][3];
    __shared__ float s_h1[KNN][HID];
    __shared__ float s_part[2][DIMD];
    __shared__ float s_agg[DIMD];
    __shared__ float s_np[4][HID];
    __shared__ float s_g1[HID];
    __shared__ float s_y[DIMD];
    __shared__ float s_red[4];
    __shared__ float s_denom, s_has;

    // ---- stage boxes, mask, x_i ----
    if (t < N_NODES) {
        const float* bb = bboxes + (size_t)(bt * N_NODES + t) * 4;
        s_cx[t] = bb[0];
        s_cy[t] = bb[1];
        s_m[t]  = pmask[bt * N_NODES + t];
    }
    if (t < DIMD) s_xi[t] = emb[(size_t)(bt * N_NODES + i) * DIMD + t];
    __syncthreads();

    // masked-out node: out = y * 0 -> zeros  (uniform branch)
    if (s_m[i] == 0) {
        if (t < DIMD) out[(size_t)(bt * N_NODES + i) * DIMD + t] = 0.f;
        return;
    }

    // ---- pairwise geometry (normalized by h_i) ----
    if (t < N_NODES) {
        float hi = fmaxf(bboxes[((size_t)(bt * N_NODES + i)) * 4 + 3], 1e-6f);
        float inv = 1.0f / hi;
        float dx = s_cx[i] - s_cx[t];
        float dy = s_cy[i] - s_cy[t];
        float dist = sqrtf(dx * dx + dy * dy + 1e-6f);
        s_dxn[t] = dx * inv;
        s_dyn[t] = dy * inv;
        s_dn[t]  = dist * inv;
    }
    __syncthreads();

    // ---- KNN select (serial on thread 0; 25x4 trivial) ----
    if (t == 0) {
        float vals[N_NODES];
        for (int j = 0; j < N_NODES; ++j) {
            bool pv = (s_m[j] != 0) && (j != i);     // mask_i already true here
            vals[j] = pv ? s_dn[j] : 1e6f;
        }
        float cnt = 0.f;
        for (int k = 0; k < KNN; ++k) {
            float best = 1e30f; int bj = 0;
            for (int j = 0; j < N_NODES; ++j) {
                if (vals[j] < best) { best = vals[j]; bj = j; }   // lowest idx on tie
            }
            vals[bj] = 1e30f;
            s_idx[k] = bj;
            float v = (best < RAD) ? 1.f : 0.f;      // best<2.5 implies pair_valid
            s_val[k] = v;
            cnt += v;
            s_e[k][0] = s_dxn[bj];
            s_e[k][1] = s_dyn[bj];
            s_e[k][2] = s_dn[bj];
        }
        s_denom = fmaxf(cnt, 1.f);
        s_has   = (cnt > 0.f) ? 1.f : 0.f;
    }
    __syncthreads();

    // ---- stage x_j for the 4 selected neighbors ----
    for (int u = t; u < KNN * DIMD; u += 256) {
        int k = u >> 7, d = u & 127;
        s_xj[k][d] = emb[(size_t)(bt * N_NODES + s_idx[k]) * DIMD + d];
    }
    __syncthreads();

    // ---- edge MLP layer 1: h1[k][h] = relu(msg_in . W1[:,h] + b1[h]) ----
    {
        int k  = t >> 6;          // neighbor 0..3
        int hh = t & 63;          // hidden unit
        const float* w = ew1 + hh;            // column hh, stride 64
        float acc = eb1[hh];
        #pragma unroll 4
        for (int c = 0; c < DIMD; ++c) acc += s_xi[c] * w[(size_t)c * HID];
        #pragma unroll 4
        for (int c = 0; c < DIMD; ++c) acc += s_xj[k][c] * w[(size_t)(DIMD + c) * HID];
        acc += s_e[k][0] * w[(size_t)(2 * DIMD + 0) * HID];
        acc += s_e[k][1] * w[(size_t)(2 * DIMD + 1) * HID];
        acc += s_e[k][2] * w[(size_t)(2 * DIMD + 2) * HID];
        s_h1[k][hh] = fmaxf(acc, 0.f);
    }
    __syncthreads();

    // ---- edge MLP layer 2 + masked aggregate ----
    {
        int g = t >> 7;           // 0: neighbors 0,1   1: neighbors 2,3
        int d = t & 127;
        const float* w = ew2 + d;             // column d, stride 128
        float acc = 0.f;
        for (int k = g * 2; k < g * 2 + 2; ++k) {
            float a = eb2[d];
            #pragma unroll 4
            for (int h = 0; h < HID; ++h) a += s_h1[k][h] * w[(size_t)h * DIMD];
            acc += a * s_val[k];              // msg * nbr_valid
        }
        s_part[g][d] = acc;
    }
    __syncthreads();
    if (t < DIMD) s_agg[t] = (s_part[0][t] + s_part[1][t]) / s_denom;
    __syncthreads();

    // ---- node MLP layer 1: g1[h] = relu(upd_in . nW1[:,h] + nb1[h]) ----
    {
        int q  = t >> 6;          // quarter of the 256-dim input
        int hh = t & 63;
        const float* w = nw1 + hh;            // column hh, stride 64
        float a = 0.f;
        int c0 = q * 64;
        #pragma unroll 4
        for (int c = c0; c < c0 + 64; ++c) {
            float xv = (c < DIMD) ? s_xi[c] : s_agg[c - DIMD];
            a += xv * w[(size_t)c * HID];
        }
        s_np[q][hh] = a;
    }
    __syncthreads();
    if (t < HID) {
        float a = nb1[t] + s_np[0][t] + s_np[1][t] + s_np[2][t] + s_np[3][t];
        s_g1[t] = fmaxf(a, 0.f);
    }
    __syncthreads();

    // ---- node MLP layer 2 + residual ----
    if (t < DIMD) {
        const float* w = nw2 + t;             // column d, stride 128
        float a = nb2[t];
        #pragma unroll 4
        for (int h = 0; h < HID; ++h) a += s_g1[h] * w[(size_t)h * DIMD];
        s_y[t] = s_xi[t] + a * s_has;
    }
    __syncthreads();

    // ---- LayerNorm(128) + write ----
    if (t < DIMD) {
        float y  = s_y[t];
        float s  = y;
        float s2 = y * y;
        #pragma unroll
        for (int o = 32; o >= 1; o >>= 1) {
            s  += __shfl_down(s, o);
            s2 += __shfl_down(s2, o);
        }
        if ((t & 63) == 0) {
            s_red[t >> 6]     = s;
            s_red[2 + (t >> 6)] = s2;
        }
    }
    __syncthreads();
    if (t < DIMD) {
        float mu  = (s_red[0] + s_red[1]) * (1.0f / 128.0f);
        float var = (s_red[2] + s_red[3]) * (1.0f / 128.0f) - mu * mu;
        float r   = rsqrtf(var + 1e-5f);
        float y   = s_y[t];
        float o   = (y - mu) * r * lng[t] + lnb[t];
        out[(size_t)(bt * N_NODES + i) * DIMD + t] = o;
    }
}

extern "C" void kernel_launch(void* const* d_in, const int* in_sizes, int n_in,
                              void* d_out, int out_size, void* d_ws, size_t ws_size,
                              hipStream_t stream) {
    const float* emb    = (const float*)d_in[0];
    const float* bboxes = (const float*)d_in[1];
    const int*   pmask  = (const int*)  d_in[2];
    const float* ew1    = (const float*)d_in[3];
    const float* eb1    = (const float*)d_in[4];
    const float* ew2    = (const float*)d_in[5];
    const float* eb2    = (const float*)d_in[6];
    const float* nw1    = (const float*)d_in[7];
    const float* nb1    = (const float*)d_in[8];
    const float* nw2    = (const float*)d_in[9];
    const float* nb2    = (const float*)d_in[10];
    const float* lng    = (const float*)d_in[11];
    const float* lnb    = (const float*)d_in[12];
    float* out = (float*)d_out;

    const int n_nodes_total = in_sizes[2];   // B*T*N = 51200
    ig_kernel<<<n_nodes_total, 256, 0, stream>>>(
        emb, bboxes, pmask, ew1, eb1, ew2, eb2,
        nw1, nb1, nw2, nb2, lng, lnb, out);
}

// Round 2
// 577.777 us; speedup vs baseline: 1.2280x; 1.2280x over previous
//
#include <hip/hip_runtime.h>

#define NN   25
#define DD   128
#define HH   64
#define KK   4
#define RADF 2.5f
#define XPAD 132   // 128 + 4 to break LDS bank alignment

__device__ __forceinline__ void fma32(float4 (&acc4)[8], float xv, const float* wrow) {
    const float4* w4 = reinterpret_cast<const float4*>(wrow);
    float4 wv[8];
#pragma unroll
    for (int q = 0; q < 8; ++q) wv[q] = w4[q];
#pragma unroll
    for (int q = 0; q < 8; ++q) {
        acc4[q].x = fmaf(xv, wv[q].x, acc4[q].x);
        acc4[q].y = fmaf(xv, wv[q].y, acc4[q].y);
        acc4[q].z = fmaf(xv, wv[q].z, acc4[q].z);
        acc4[q].w = fmaf(xv, wv[q].w, acc4[q].w);
    }
}

__device__ __forceinline__ void fma16(float4 (&acc4)[4], float xv, const float* wrow) {
    const float4* w4 = reinterpret_cast<const float4*>(wrow);
    float4 wv[4];
#pragma unroll
    for (int q = 0; q < 4; ++q) wv[q] = w4[q];
#pragma unroll
    for (int q = 0; q < 4; ++q) {
        acc4[q].x = fmaf(xv, wv[q].x, acc4[q].x);
        acc4[q].y = fmaf(xv, wv[q].y, acc4[q].y);
        acc4[q].z = fmaf(xv, wv[q].z, acc4[q].z);
        acc4[q].w = fmaf(xv, wv[q].w, acc4[q].w);
    }
}

__global__ __launch_bounds__(256) void ig2_kernel(
    const float* __restrict__ emb,      // [BT, 25, 128]
    const float* __restrict__ bboxes,   // [BT, 25, 4]
    const int*   __restrict__ pmask,    // [BT, 25]
    const float* __restrict__ ew1,      // [259, 64]
    const float* __restrict__ eb1,      // [64]
    const float* __restrict__ ew2,      // [64, 128]
    const float* __restrict__ eb2,      // [128]
    const float* __restrict__ nw1,      // [256, 64]
    const float* __restrict__ nb1,      // [64]
    const float* __restrict__ nw2,      // [64, 128]
    const float* __restrict__ nb2,      // [128]
    const float* __restrict__ lng,      // [128]
    const float* __restrict__ lnb,      // [128]
    float* __restrict__ out)            // [BT, 25, 128]
{
    const int bt   = blockIdx.x;
    const int t    = threadIdx.x;
    const int wave = t >> 6;
    const int lane = t & 63;

    __shared__ float s_x[NN][XPAD];        // 13.2 KB, live whole kernel
    __shared__ float s_h1[100][HH];        // 25.6 KB; reused as p4 partials after P3a
    __shared__ float s_hsum[NN][HH];       // 6.4 KB;  reused as g1 after P3b
    __shared__ float s_agg[NN][XPAD];      // 13.2 KB; reused as delta after P4
    __shared__ float s_e[NN][KK][3];
    __shared__ float s_val[NN][KK];
    __shared__ int   s_idx[NN][KK];
    __shared__ float s_cx[NN], s_cy[NN], s_hh[NN];
    __shared__ int   s_m[NN];
    __shared__ float s_cnt[NN], s_invd[NN], s_has[NN];

    float* s_p4 = &s_h1[0][0];             // [2*25][64] partials for node-L1
    float* s_g1 = &s_hsum[0][0];           // [25][64]  node-L1 activations

    // ---------------- P0: stage frame ----------------
    {
        const float* src = emb + (size_t)bt * (NN * DD);
        for (int u = t; u < NN * (DD / 4); u += 256) {
            int row = u >> 5, q = u & 31;
            reinterpret_cast<float4*>(&s_x[row][0])[q] =
                reinterpret_cast<const float4*>(src + row * DD)[q];
        }
        if (t < NN) {
            const float* bb = bboxes + ((size_t)bt * NN + t) * 4;
            s_cx[t] = bb[0];
            s_cy[t] = bb[1];
            s_hh[t] = fmaxf(bb[3], 1e-6f);
            s_m[t]  = pmask[(size_t)bt * NN + t];
        }
    }
    __syncthreads();

    // ---------------- P1: geometry + KNN (lane-parallel over nodes) ----------------
    if (t < NN) {
        const int n    = t;
        const float inv = 1.0f / s_hh[n];
        const float cxn = s_cx[n], cyn = s_cy[n];
        const int   mn  = s_m[n];
        float best[KK] = {1e30f, 1e30f, 1e30f, 1e30f};
        int   bidx[KK] = {0, 0, 0, 0};
        for (int j = 0; j < NN; ++j) {
            float dx = cxn - s_cx[j], dy = cyn - s_cy[j];
            float dn = sqrtf(fmaf(dx, dx, fmaf(dy, dy, 1e-6f))) * inv;
            bool  pv = (mn != 0) && (s_m[j] != 0) && (j != n);
            float cv = pv ? dn : 1e6f;
            int   ci = j;
#pragma unroll
            for (int kk = 0; kk < KK; ++kk) {       // stable insertion (ties keep lowest j)
                if (cv < best[kk]) {
                    float tv = best[kk]; best[kk] = cv; cv = tv;
                    int   ti = bidx[kk]; bidx[kk] = ci; ci = ti;
                }
            }
        }
        float cnt = 0.f;
#pragma unroll
        for (int k = 0; k < KK; ++k) {
            int bj = bidx[k];
            s_idx[n][k] = bj;
            float val = (best[k] < RADF) ? 1.f : 0.f;
            cnt += val;
            s_val[n][k] = val;
            float dx = cxn - s_cx[bj], dy = cyn - s_cy[bj];
            s_e[n][k][0] = dx * inv;
            s_e[n][k][1] = dy * inv;
            s_e[n][k][2] = sqrtf(fmaf(dx, dx, fmaf(dy, dy, 1e-6f))) * inv;
        }
        s_cnt[n]  = cnt;
        s_invd[n] = 1.0f / fmaxf(cnt, 1.0f);
        s_has[n]  = (cnt > 0.f) ? 1.f : 0.f;
    }
    __syncthreads();

    // ---------------- P2: edge MLP L1  [100 x 259] @ [259 x 64] ----------------
    // wave -> (row half, h strip of 32); lane -> edge row. Weights broadcast via float4.
    {
        const int h0 = __builtin_amdgcn_readfirstlane((wave >> 1) * 32);
        const int r  = ((wave & 1) << 6) + lane;   // 0..127, rows >=100 padded
        const int rr = (r < 100) ? r : 99;
        const int n  = rr >> 2, k = rr & 3;
        const int jj = s_idx[n][k];
        const float* xi = &s_x[n][0];
        const float* xj = &s_x[jj][0];
        float4 acc4[8];
        {
            const float4* b4 = reinterpret_cast<const float4*>(eb1 + h0);
#pragma unroll
            for (int q = 0; q < 8; ++q) acc4[q] = b4[q];
        }
        const float* w = ew1 + h0;
#pragma unroll 2
        for (int c = 0; c < DD; ++c) fma32(acc4, xi[c], w + (size_t)c * HH);
#pragma unroll 2
        for (int c = 0; c < DD; ++c) fma32(acc4, xj[c], w + (size_t)(DD + c) * HH);
        fma32(acc4, s_e[n][k][0], w + (size_t)(2 * DD + 0) * HH);
        fma32(acc4, s_e[n][k][1], w + (size_t)(2 * DD + 1) * HH);
        fma32(acc4, s_e[n][k][2], w + (size_t)(2 * DD + 2) * HH);
        if (r < 100) {
            float4* dst = reinterpret_cast<float4*>(&s_h1[r][h0]);
#pragma unroll
            for (int q = 0; q < 8; ++q) {
                float4 v = acc4[q];
                v.x = fmaxf(v.x, 0.f); v.y = fmaxf(v.y, 0.f);
                v.z = fmaxf(v.z, 0.f); v.w = fmaxf(v.w, 0.f);
                dst[q] = v;
            }
        }
    }
    __syncthreads();

    // ---------------- P3a: hsum[n][c] = sum_k val * h1  (linear L2 commutes with agg) ----
    {
        const int c = lane;
        for (int n = wave; n < NN; n += 4) {
            float a = 0.f;
#pragma unroll
            for (int k = 0; k < KK; ++k) a = fmaf(s_val[n][k], s_h1[n * KK + k][c], a);
            s_hsum[n][c] = a;
        }
    }
    __syncthreads();

    // ---------------- P3b: agg = (hsum @ W2 + cnt*b2) * invd ----------------
    {
        const int d    = t & 127;
        const int g    = t >> 7;
        const int nlo  = g ? 13 : 0;
        const int nnum = g ? 12 : 13;
        float accn[13];
#pragma unroll
        for (int q = 0; q < 13; ++q) accn[q] = 0.f;
        for (int c = 0; c < HH; c += 2) {
            float w0 = ew2[(size_t)c * DD + d];
            float w1 = ew2[(size_t)(c + 1) * DD + d];
#pragma unroll
            for (int q = 0; q < 13; ++q) {
                if (q < nnum) {
                    float2 hv = *reinterpret_cast<const float2*>(&s_hsum[nlo + q][c]);
                    accn[q] = fmaf(hv.x, w0, fmaf(hv.y, w1, accn[q]));
                }
            }
        }
        float b2d = eb2[d];
#pragma unroll
        for (int q = 0; q < 13; ++q) {
            if (q < nnum) {
                int n = nlo + q;
                s_agg[n][d] = s_invd[n] * (accn[q] + s_cnt[n] * b2d);
            }
        }
    }
    __syncthreads();

    // ---------------- P4: node MLP L1 partials  [25 x 256] @ [256 x 64] ----------------
    // lane -> (node, c-half); wave -> h strip of 16. Each lane does 128 c's.
    {
        const int h0  = __builtin_amdgcn_readfirstlane(wave * 16);
        const bool act = lane < 2 * NN;
        const int n   = act ? (lane >> 1) : (NN - 1);
        const int ch  = lane & 1;
        const float* in = ch ? &s_agg[n][0] : &s_x[n][0];
        const float* w  = nw1 + (size_t)ch * DD * HH + h0;
        float4 acc4[4];
#pragma unroll
        for (int q = 0; q < 4; ++q) acc4[q] = make_float4(0.f, 0.f, 0.f, 0.f);
#pragma unroll 2
        for (int c = 0; c < DD; ++c) fma16(acc4, in[c], w + (size_t)c * HH);
        if (act) {
            float4* dst = reinterpret_cast<float4*>(&s_p4[((ch * NN) + n) * HH + h0]);
#pragma unroll
            for (int q = 0; q < 4; ++q) dst[q] = acc4[q];
        }
    }
    __syncthreads();

    // ---------------- P4b: combine halves + bias + relu -> g1 ----------------
    for (int u = t; u < NN * HH; u += 256) {
        int n = u >> 6, h = u & 63;
        float v = nb1[h] + s_p4[n * HH + h] + s_p4[(NN + n) * HH + h];
        s_g1[n * HH + h] = fmaxf(v, 0.f);
    }
    __syncthreads();

    // ---------------- P5: node MLP L2 -> delta (stored in s_agg) ----------------
    {
        const int d    = t & 127;
        const int g    = t >> 7;
        const int nlo  = g ? 13 : 0;
        const int nnum = g ? 12 : 13;
        float accn[13];
#pragma unroll
        for (int q = 0; q < 13; ++q) accn[q] = 0.f;
        for (int h = 0; h < HH; h += 2) {
            float w0 = nw2[(size_t)h * DD + d];
            float w1 = nw2[(size_t)(h + 1) * DD + d];
#pragma unroll
            for (int q = 0; q < 13; ++q) {
                if (q < nnum) {
                    float2 gv = *reinterpret_cast<const float2*>(&s_g1[(nlo + q) * HH + h]);
                    accn[q] = fmaf(gv.x, w0, fmaf(gv.y, w1, accn[q]));
                }
            }
        }
        float b = nb2[d];
#pragma unroll
        for (int q = 0; q < 13; ++q) {
            if (q < nnum) s_agg[nlo + q][d] = b + accn[q];
        }
    }
    __syncthreads();

    // ---------------- P6: residual + LayerNorm + mask + store (wave per node) -------
    {
        for (int n = wave; n < NN; n += 4) {
            float has = s_has[n];
            float y0 = fmaf(s_agg[n][lane],      has, s_x[n][lane]);
            float y1 = fmaf(s_agg[n][lane + 64], has, s_x[n][lane + 64]);
            float s  = y0 + y1;
            float s2 = fmaf(y0, y0, y1 * y1);
#pragma unroll
            for (int o = 32; o >= 1; o >>= 1) {
                s  += __shfl_xor(s, o);
                s2 += __shfl_xor(s2, o);
            }
            float mu  = s * (1.0f / 128.0f);
            float var = s2 * (1.0f / 128.0f) - mu * mu;
            float rs  = rsqrtf(var + 1e-5f);
            float mk  = s_m[n] ? 1.f : 0.f;
            float* op = out + (size_t)bt * (NN * DD) + n * DD;
            op[lane]      = fmaf((y0 - mu) * rs, lng[lane],      lnb[lane])      * mk;
            op[lane + 64] = fmaf((y1 - mu) * rs, lng[lane + 64], lnb[lane + 64]) * mk;
        }
    }
}

extern "C" void kernel_launch(void* const* d_in, const int* in_sizes, int n_in,
                              void* d_out, int out_size, void* d_ws, size_t ws_size,
                              hipStream_t stream) {
    const float* emb    = (const float*)d_in[0];
    const float* bboxes = (const float*)d_in[1];
    const int*   pmask  = (const int*)  d_in[2];
    const float* ew1    = (const float*)d_in[3];
    const float* eb1    = (const float*)d_in[4];
    const float* ew2    = (const float*)d_in[5];
    const float* eb2    = (const float*)d_in[6];
    const float* nw1    = (const float*)d_in[7];
    const float* nb1    = (const float*)d_in[8];
    const float* nw2    = (const float*)d_in[9];
    const float* nb2    = (const float*)d_in[10];
    const float* lng    = (const float*)d_in[11];
    const float* lnb    = (const float*)d_in[12];
    float* out = (float*)d_out;

    const int BT = in_sizes[2] / NN;   // 2048 frames
    ig2_kernel<<<BT, 256, 0, stream>>>(
        emb, bboxes, pmask, ew1, eb1, ew2, eb2,
        nw1, nb1, nw2, nb2, lng, lnb, out);
}

// Round 3
// 468.001 us; speedup vs baseline: 1.5161x; 1.2346x over previous
//
#include <hip/hip_runtime.h>

#define NN   25
#define DD   128
#define HH   64
#define KK   4
#define RADF 2.5f
#define XP   132   // 128+4 floats, row base stays 16B-aligned
#define HP   68    // 64+4

__device__ __forceinline__ void fma4(float4& a, float x, float4 w) {
    a.x = fmaf(x, w.x, a.x); a.y = fmaf(x, w.y, a.y);
    a.z = fmaf(x, w.z, a.z); a.w = fmaf(x, w.w, a.w);
}
__device__ __forceinline__ float rw(float v0, float a0, float v1, float a1,
                                    float v2, float a2, float v3, float a3) {
    return fmaf(v0, fmaxf(a0, 0.f), fmaf(v1, fmaxf(a1, 0.f),
           fmaf(v2, fmaxf(a2, 0.f), v3 * fmaxf(a3, 0.f))));
}

__global__ __launch_bounds__(256, 4) void ig3_kernel(
    const float* __restrict__ emb,      // [BT, 25, 128]
    const float* __restrict__ bboxes,   // [BT, 25, 4]
    const int*   __restrict__ pmask,    // [BT, 25]
    const float* __restrict__ ew1,      // [259, 64]
    const float* __restrict__ eb1,      // [64]
    const float* __restrict__ ew2,      // [64, 128]
    const float* __restrict__ eb2,      // [128]
    const float* __restrict__ nw1,      // [256, 64]
    const float* __restrict__ nb1,      // [64]
    const float* __restrict__ nw2,      // [64, 128]
    const float* __restrict__ nb2,      // [128]
    const float* __restrict__ lng,      // [128]
    const float* __restrict__ lnb,      // [128]
    float* __restrict__ out)            // [BT, 25, 128]
{
    const int bt   = blockIdx.x;
    const int t    = threadIdx.x;
    const int wave = t >> 6;
    const int lane = t & 63;

    __shared__ float s_x[NN][XP];       // 13.2 KB  (x, whole kernel)
    __shared__ float s_hsum[NN][HP];    // 6.8 KB   (hsum, then g1)
    __shared__ float s_agg[NN][XP];     // 13.2 KB  (agg, then delta)
    __shared__ float s_e[NN][KK][3];
    __shared__ float s_val[NN][KK];
    __shared__ int   s_idx[NN][KK];
    __shared__ float s_cx[NN], s_cy[NN], s_hv[NN];
    __shared__ int   s_m[NN];
    __shared__ float s_cnt[NN], s_invd[NN], s_has[NN];

    // ---------------- P0: stage frame ----------------
    {
        const float* src = emb + (size_t)bt * (NN * DD);
        for (int u = t; u < NN * 32; u += 256) {
            int row = u >> 5, q = u & 31;
            reinterpret_cast<float4*>(&s_x[row][0])[q] =
                reinterpret_cast<const float4*>(src + row * DD)[q];
        }
        if (t < NN) {
            const float* bb = bboxes + ((size_t)bt * NN + t) * 4;
            s_cx[t] = bb[0];
            s_cy[t] = bb[1];
            s_hv[t] = fmaxf(bb[3], 1e-6f);
            s_m[t]  = pmask[(size_t)bt * NN + t];
        }
    }
    __syncthreads();

    // ---------------- P1: geometry + KNN (lane-parallel over nodes) ----------------
    if (t < NN) {
        const int n     = t;
        const float inv = 1.0f / s_hv[n];
        const float cxn = s_cx[n], cyn = s_cy[n];
        const int   mn  = s_m[n];
        float best[KK] = {1e30f, 1e30f, 1e30f, 1e30f};
        int   bidx[KK] = {0, 0, 0, 0};
        for (int j = 0; j < NN; ++j) {
            float dx = cxn - s_cx[j], dy = cyn - s_cy[j];
            float dn = sqrtf(fmaf(dx, dx, fmaf(dy, dy, 1e-6f))) * inv;
            bool  pv = (mn != 0) && (s_m[j] != 0) && (j != n);
            float cv = pv ? dn : 1e6f;
            int   ci = j;
#pragma unroll
            for (int kk = 0; kk < KK; ++kk) {     // stable insertion, ties keep lowest j
                if (cv < best[kk]) {
                    float tv = best[kk]; best[kk] = cv; cv = tv;
                    int   ti = bidx[kk]; bidx[kk] = ci; ci = ti;
                }
            }
        }
        float cnt = 0.f;
#pragma unroll
        for (int k = 0; k < KK; ++k) {
            int bj = bidx[k];
            s_idx[n][k] = bj;
            float val = (best[k] < RADF) ? 1.f : 0.f;
            cnt += val;
            s_val[n][k] = val;
            float dx = cxn - s_cx[bj], dy = cyn - s_cy[bj];
            s_e[n][k][0] = dx * inv;
            s_e[n][k][1] = dy * inv;
            s_e[n][k][2] = sqrtf(fmaf(dx, dx, fmaf(dy, dy, 1e-6f))) * inv;
        }
        s_cnt[n]  = cnt;
        s_invd[n] = 1.0f / fmaxf(cnt, 1.0f);
        s_has[n]  = (cnt > 0.f) ? 1.f : 0.f;
    }
    __syncthreads();

    const bool act = (t < 8 * NN);              // 200 worker threads
    const int  nA  = act ? (t >> 3) : (NN - 1); // node
    const int  c8  = t & 7;                     // strip id

    // ---------------- P2: edge MLP L1 + relu + val-weighted k-sum (fused) --------
    // thread = (node, 8-col strip). x_i partial computed once, shared by 4 edges.
    {
        const int j0 = s_idx[nA][0], j1 = s_idx[nA][1];
        const int j2 = s_idx[nA][2], j3 = s_idx[nA][3];
        const float* wp = ew1 + c8 * 8;
        float4 xa0 = reinterpret_cast<const float4*>(eb1 + c8 * 8)[0];
        float4 xa1 = reinterpret_cast<const float4*>(eb1 + c8 * 8)[1];
        const float* xi = &s_x[nA][0];
#pragma unroll 4
        for (int c = 0; c < DD; ++c) {
            float  xv = xi[c];
            float4 w0 = reinterpret_cast<const float4*>(wp)[0];
            float4 w1 = reinterpret_cast<const float4*>(wp)[1];
            fma4(xa0, xv, w0); fma4(xa1, xv, w1);
            wp += HH;
        }
        float4 a00 = xa0, a01 = xa1, a10 = xa0, a11 = xa1;
        float4 a20 = xa0, a21 = xa1, a30 = xa0, a31 = xa1;
        const float* xj0 = &s_x[j0][0];
        const float* xj1 = &s_x[j1][0];
        const float* xj2 = &s_x[j2][0];
        const float* xj3 = &s_x[j3][0];
#pragma unroll 2
        for (int c = 0; c < DD; ++c) {
            float4 w0 = reinterpret_cast<const float4*>(wp)[0];
            float4 w1 = reinterpret_cast<const float4*>(wp)[1];
            wp += HH;
            float x0 = xj0[c], x1 = xj1[c], x2 = xj2[c], x3 = xj3[c];
            fma4(a00, x0, w0); fma4(a01, x0, w1);
            fma4(a10, x1, w0); fma4(a11, x1, w1);
            fma4(a20, x2, w0); fma4(a21, x2, w1);
            fma4(a30, x3, w0); fma4(a31, x3, w1);
        }
#pragma unroll
        for (int cc = 0; cc < 3; ++cc) {
            float4 w0 = reinterpret_cast<const float4*>(wp)[0];
            float4 w1 = reinterpret_cast<const float4*>(wp)[1];
            wp += HH;
            fma4(a00, s_e[nA][0][cc], w0); fma4(a01, s_e[nA][0][cc], w1);
            fma4(a10, s_e[nA][1][cc], w0); fma4(a11, s_e[nA][1][cc], w1);
            fma4(a20, s_e[nA][2][cc], w0); fma4(a21, s_e[nA][2][cc], w1);
            fma4(a30, s_e[nA][3][cc], w0); fma4(a31, s_e[nA][3][cc], w1);
        }
        float v0 = s_val[nA][0], v1 = s_val[nA][1];
        float v2 = s_val[nA][2], v3 = s_val[nA][3];
        float4 h0, h1;
        h0.x = rw(v0, a00.x, v1, a10.x, v2, a20.x, v3, a30.x);
        h0.y = rw(v0, a00.y, v1, a10.y, v2, a20.y, v3, a30.y);
        h0.z = rw(v0, a00.z, v1, a10.z, v2, a20.z, v3, a30.z);
        h0.w = rw(v0, a00.w, v1, a10.w, v2, a20.w, v3, a30.w);
        h1.x = rw(v0, a01.x, v1, a11.x, v2, a21.x, v3, a31.x);
        h1.y = rw(v0, a01.y, v1, a11.y, v2, a21.y, v3, a31.y);
        h1.z = rw(v0, a01.z, v1, a11.z, v2, a21.z, v3, a31.z);
        h1.w = rw(v0, a01.w, v1, a11.w, v2, a21.w, v3, a31.w);
        if (act) {
            reinterpret_cast<float4*>(&s_hsum[nA][c8 * 8])[0] = h0;
            reinterpret_cast<float4*>(&s_hsum[nA][c8 * 8])[1] = h1;
        }
    }
    __syncthreads();

    // ---------------- P3b: agg = (hsum @ W2 + cnt*b2) * invd  (16-col strips) ----
    {
        const int d0 = c8 * 16;
        float4 a[4];
#pragma unroll
        for (int q = 0; q < 4; ++q) a[q] = make_float4(0.f, 0.f, 0.f, 0.f);
        const float* hp = &s_hsum[nA][0];
        const float* wp = ew2 + d0;
#pragma unroll 4
        for (int c = 0; c < HH; ++c) {
            float hv = hp[c];
#pragma unroll
            for (int q = 0; q < 4; ++q)
                fma4(a[q], hv, reinterpret_cast<const float4*>(wp)[q]);
            wp += DD;
        }
        if (act) {
            float cn = s_cnt[nA], iv = s_invd[nA];
            const float4* b4 = reinterpret_cast<const float4*>(eb2 + d0);
#pragma unroll
            for (int q = 0; q < 4; ++q) {
                float4 b = b4[q], r;
                r.x = iv * fmaf(cn, b.x, a[q].x);
                r.y = iv * fmaf(cn, b.y, a[q].y);
                r.z = iv * fmaf(cn, b.z, a[q].z);
                r.w = iv * fmaf(cn, b.w, a[q].w);
                reinterpret_cast<float4*>(&s_agg[nA][d0])[q] = r;
            }
        }
    }
    __syncthreads();

    // ---------------- P4: node MLP L1 -> g1 (aliased into s_hsum) ----------------
    {
        const float* wp = nw1 + c8 * 8;
        float4 a0 = reinterpret_cast<const float4*>(nb1 + c8 * 8)[0];
        float4 a1 = reinterpret_cast<const float4*>(nb1 + c8 * 8)[1];
        const float* xi = &s_x[nA][0];
#pragma unroll 4
        for (int c = 0; c < DD; ++c) {
            float xv = xi[c];
            fma4(a0, xv, reinterpret_cast<const float4*>(wp)[0]);
            fma4(a1, xv, reinterpret_cast<const float4*>(wp)[1]);
            wp += HH;
        }
        const float* ag = &s_agg[nA][0];
#pragma unroll 4
        for (int c = 0; c < DD; ++c) {
            float xv = ag[c];
            fma4(a0, xv, reinterpret_cast<const float4*>(wp)[0]);
            fma4(a1, xv, reinterpret_cast<const float4*>(wp)[1]);
            wp += HH;
        }
        a0.x = fmaxf(a0.x, 0.f); a0.y = fmaxf(a0.y, 0.f);
        a0.z = fmaxf(a0.z, 0.f); a0.w = fmaxf(a0.w, 0.f);
        a1.x = fmaxf(a1.x, 0.f); a1.y = fmaxf(a1.y, 0.f);
        a1.z = fmaxf(a1.z, 0.f); a1.w = fmaxf(a1.w, 0.f);
        if (act) {
            reinterpret_cast<float4*>(&s_hsum[nA][c8 * 8])[0] = a0;   // g1
            reinterpret_cast<float4*>(&s_hsum[nA][c8 * 8])[1] = a1;
        }
    }
    __syncthreads();

    // ---------------- P5: node MLP L2 -> delta (overwrites s_agg) ----------------
    {
        const int d0 = c8 * 16;
        float4 a[4];
#pragma unroll
        for (int q = 0; q < 4; ++q) a[q] = make_float4(0.f, 0.f, 0.f, 0.f);
        const float* gp = &s_hsum[nA][0];
        const float* wp = nw2 + d0;
#pragma unroll 4
        for (int h = 0; h < HH; ++h) {
            float gv = gp[h];
#pragma unroll
            for (int q = 0; q < 4; ++q)
                fma4(a[q], gv, reinterpret_cast<const float4*>(wp)[q]);
            wp += DD;
        }
        if (act) {
            const float4* b4 = reinterpret_cast<const float4*>(nb2 + d0);
#pragma unroll
            for (int q = 0; q < 4; ++q) {
                float4 b = b4[q], r;
                r.x = a[q].x + b.x; r.y = a[q].y + b.y;
                r.z = a[q].z + b.z; r.w = a[q].w + b.w;
                reinterpret_cast<float4*>(&s_agg[nA][d0])[q] = r;     // delta
            }
        }
    }
    __syncthreads();

    // ---------------- P6: residual + LayerNorm + mask + store (wave per node) ----
    {
        for (int n = wave; n < NN; n += 4) {
            float has = s_has[n];
            float y0 = fmaf(s_agg[n][lane],      has, s_x[n][lane]);
            float y1 = fmaf(s_agg[n][lane + 64], has, s_x[n][lane + 64]);
            float s  = y0 + y1;
            float s2 = fmaf(y0, y0, y1 * y1);
#pragma unroll
            for (int o = 32; o >= 1; o >>= 1) {
                s  += __shfl_xor(s, o);
                s2 += __shfl_xor(s2, o);
            }
            float mu  = s * (1.0f / 128.0f);
            float var = s2 * (1.0f / 128.0f) - mu * mu;
            float rs  = rsqrtf(var + 1e-5f);
            float mk  = s_m[n] ? 1.f : 0.f;
            float* op = out + (size_t)bt * (NN * DD) + n * DD;
            op[lane]      = fmaf((y0 - mu) * rs, lng[lane],      lnb[lane])      * mk;
            op[lane + 64] = fmaf((y1 - mu) * rs, lng[lane + 64], lnb[lane + 64]) * mk;
        }
    }
}

extern "C" void kernel_launch(void* const* d_in, const int* in_sizes, int n_in,
                              void* d_out, int out_size, void* d_ws, size_t ws_size,
                              hipStream_t stream) {
    const float* emb    = (const float*)d_in[0];
    const float* bboxes = (const float*)d_in[1];
    const int*   pmask  = (const int*)  d_in[2];
    const float* ew1    = (const float*)d_in[3];
    const float* eb1    = (const float*)d_in[4];
    const float* ew2    = (const float*)d_in[5];
    const float* eb2    = (const float*)d_in[6];
    const float* nw1    = (const float*)d_in[7];
    const float* nb1    = (const float*)d_in[8];
    const float* nw2    = (const float*)d_in[9];
    const float* nb2    = (const float*)d_in[10];
    const float* lng    = (const float*)d_in[11];
    const float* lnb    = (const float*)d_in[12];
    float* out = (float*)d_out;

    const int BT = in_sizes[2] / NN;   // 2048 frames
    ig3_kernel<<<BT, 256, 0, stream>>>(
        emb, bboxes, pmask, ew1, eb1, ew2, eb2,
        nw1, nb1, nw2, nb2, lng, lnb, out);
}

// Round 4
// 82.283 us; speedup vs baseline: 8.6228x; 5.6877x over previous
//
#include <hip/hip_runtime.h>

#define NN   25
#define DD   128
#define HH   64
#define KK   4
#define RADF 2.5f

#define XBP  136   // ushort stride for [25][128] bf16 rows (272B, 16B-aligned)
#define HSP  72    // ushort stride for [25][64] bf16 rows (144B)
#define HXP  68    // float stride for hxi rows

// ws layout (ushort units)
#define O_W1T 0        // [64][264]   ew1^T  (k<259)
#define O_W2T 16896    // [128][64]   ew2^T
#define O_N1T 25088    // [64][256]   nw1^T
#define O_N2T 41472    // [128][64]   nw2^T

typedef __attribute__((ext_vector_type(8))) short  short8;
typedef __attribute__((ext_vector_type(4))) float  f32x4;

__device__ __forceinline__ ushort f2bf(float x) {
    uint u = __float_as_uint(x);
    u += 0x7fffu + ((u >> 16) & 1u);          // RNE
    return (ushort)(u >> 16);
}
__device__ __forceinline__ uint pack2(float a, float b) {
    return (uint)f2bf(a) | ((uint)f2bf(b) << 16);
}
#define MFMA16(a, b, c) __builtin_amdgcn_mfma_f32_16x16x32_bf16((a), (b), (c), 0, 0, 0)

__global__ void prep_kernel(const float* __restrict__ ew1, const float* __restrict__ ew2,
                            const float* __restrict__ nw1, const float* __restrict__ nw2,
                            ushort* __restrict__ w) {
    int tid = blockIdx.x * blockDim.x + threadIdx.x;
    int stride = gridDim.x * blockDim.x;
    for (int e = tid; e < 259 * 64; e += stride) {
        int k = e >> 6, c = e & 63;
        w[O_W1T + c * 264 + k] = f2bf(ew1[e]);
    }
    for (int e = tid; e < 64 * 128; e += stride) {
        int k = e >> 7, d = e & 127;
        w[O_W2T + d * 64 + k] = f2bf(ew2[e]);
    }
    for (int e = tid; e < 256 * 64; e += stride) {
        int k = e >> 6, c = e & 63;
        w[O_N1T + c * 256 + k] = f2bf(nw1[e]);
    }
    for (int e = tid; e < 64 * 128; e += stride) {
        int k = e >> 7, d = e & 127;
        w[O_N2T + d * 64 + k] = f2bf(nw2[e]);
    }
}

__global__ __launch_bounds__(256, 4) void ig4_kernel(
    const float* __restrict__ emb,      // [BT,25,128]
    const float* __restrict__ bboxes,   // [BT,25,4]
    const int*   __restrict__ pmask,    // [BT,25]
    const float* __restrict__ ew1f,     // [259,64] f32 (for e-rows 256..258)
    const float* __restrict__ eb1,
    const float* __restrict__ eb2,
    const float* __restrict__ nb1,
    const float* __restrict__ nb2,
    const float* __restrict__ lng,
    const float* __restrict__ lnb,
    const ushort* __restrict__ W,       // prepped bf16 transposed weights
    float* __restrict__ out)
{
    const int bt  = blockIdx.x;
    const int t   = threadIdx.x;
    const int wv  = t >> 6;
    const int ln  = t & 63;
    const int g   = ln >> 4;     // k-chunk group (0..3)
    const int r16 = ln & 15;

    __shared__ ushort s_xb[NN * XBP];     // x bf16
    __shared__ ushort s_ag[NN * XBP];     // agg bf16
    __shared__ ushort s_hs[NN * HSP];     // hsum bf16
    __shared__ ushort s_g1[NN * HSP];     // g1 bf16
    __shared__ float  s_hxi[NN * HXP];    // xi-part of edge-L1, f32
    __shared__ float  s_red[32][2][2];
    __shared__ float  s_e[NN][KK][3];
    __shared__ float  s_val[NN][KK];
    __shared__ int    s_idx[NN][KK];
    __shared__ float  s_cx[NN], s_cy[NN], s_hv[NN];
    __shared__ int    s_m[NN];
    __shared__ float  s_cnt[NN], s_invd[NN], s_has[NN];

    // ---------------- P0: stage x (bf16) + boxes/mask ----------------
    {
        const float4* src4 = reinterpret_cast<const float4*>(emb + (size_t)bt * (NN * DD));
        for (int u = t; u < NN * 16; u += 256) {
            int row = u >> 4, q = u & 15;
            float4 f0 = src4[row * 32 + q * 2];
            float4 f1 = src4[row * 32 + q * 2 + 1];
            uint4 p;
            p.x = pack2(f0.x, f0.y); p.y = pack2(f0.z, f0.w);
            p.z = pack2(f1.x, f1.y); p.w = pack2(f1.z, f1.w);
            *reinterpret_cast<uint4*>(&s_xb[row * XBP + q * 8]) = p;
        }
        if (t < NN) {
            const float* bb = bboxes + ((size_t)bt * NN + t) * 4;
            s_cx[t] = bb[0];
            s_cy[t] = bb[1];
            s_hv[t] = fmaxf(bb[3], 1e-6f);
            s_m[t]  = pmask[(size_t)bt * NN + t];
        }
    }
    __syncthreads();

    // ---------------- P1: geometry + KNN (f32, identical to ref ordering) --------
    if (t < NN) {
        const int n     = t;
        const float inv = 1.0f / s_hv[n];
        const float cxn = s_cx[n], cyn = s_cy[n];
        const int   mn  = s_m[n];
        float best[KK] = {1e30f, 1e30f, 1e30f, 1e30f};
        int   bidx[KK] = {0, 0, 0, 0};
        for (int j = 0; j < NN; ++j) {
            float dx = cxn - s_cx[j], dy = cyn - s_cy[j];
            float dn = sqrtf(fmaf(dx, dx, fmaf(dy, dy, 1e-6f))) * inv;
            bool  pv = (mn != 0) && (s_m[j] != 0) && (j != n);
            float cv = pv ? dn : 1e6f;
            int   ci = j;
#pragma unroll
            for (int kk = 0; kk < KK; ++kk) {
                if (cv < best[kk]) {
                    float tv = best[kk]; best[kk] = cv; cv = tv;
                    int   ti = bidx[kk]; bidx[kk] = ci; ci = ti;
                }
            }
        }
        float cnt = 0.f;
#pragma unroll
        for (int k = 0; k < KK; ++k) {
            int bj = bidx[k];
            s_idx[n][k] = bj;
            float val = (best[k] < RADF) ? 1.f : 0.f;
            cnt += val;
            s_val[n][k] = val;
            float dx = cxn - s_cx[bj], dy = cyn - s_cy[bj];
            s_e[n][k][0] = dx * inv;
            s_e[n][k][1] = dy * inv;
            s_e[n][k][2] = sqrtf(fmaf(dx, dx, fmaf(dy, dy, 1e-6f))) * inv;
        }
        s_cnt[n]  = cnt;
        s_invd[n] = 1.0f / fmaxf(cnt, 1.0f);
        s_has[n]  = (cnt > 0.f) ? 1.f : 0.f;
    }
    __syncthreads();

    // ---------------- E1a: hxi[25][64] = x @ W1[0:128]  (waves 0,1) ----------------
    if (wv < 2) {
        const int mt = wv;
        int n = 16 * mt + r16; if (n > 24) n = 24;
        const ushort* A = s_xb + n * XBP + g * 8;
        f32x4 c[4] = {{0,0,0,0},{0,0,0,0},{0,0,0,0},{0,0,0,0}};
#pragma unroll
        for (int kt = 0; kt < 4; ++kt) {
            short8 a = *reinterpret_cast<const short8*>(A + kt * 32);
#pragma unroll
            for (int nt = 0; nt < 4; ++nt) {
                const short8 b = *reinterpret_cast<const short8*>(
                    W + O_W1T + (size_t)(16 * nt + r16) * 264 + kt * 32 + g * 8);
                c[nt] = MFMA16(a, b, c[nt]);
            }
        }
#pragma unroll
        for (int q = 0; q < 4; ++q) {
            int nr = 16 * mt + 4 * g + q;
            if (nr < 25) {
#pragma unroll
                for (int nt = 0; nt < 4; ++nt)
                    s_hxi[nr * HXP + 16 * nt + r16] = c[nt][q];
            }
        }
    }
    __syncthreads();

    // ---------------- E1b: xj GEMM + fused relu/val-k-sum -> hsum bf16 -------------
    for (int T = wv; T < 7; T += 4) {
        int r = 16 * T + r16; if (r > 99) r = 99;
        const int jn = s_idx[r >> 2][r & 3];
        const ushort* A = s_xb + jn * XBP + g * 8;
        f32x4 c[4] = {{0,0,0,0},{0,0,0,0},{0,0,0,0},{0,0,0,0}};
#pragma unroll
        for (int kt = 0; kt < 4; ++kt) {
            short8 a = *reinterpret_cast<const short8*>(A + kt * 32);
#pragma unroll
            for (int nt = 0; nt < 4; ++nt) {
                const short8 b = *reinterpret_cast<const short8*>(
                    W + O_W1T + (size_t)(16 * nt + r16) * 264 + 128 + kt * 32 + g * 8);
                c[nt] = MFMA16(a, b, c[nt]);
            }
        }
        const int n = 4 * T + g;
        if (n < 25) {
            float v[4] = {s_val[n][0], s_val[n][1], s_val[n][2], s_val[n][3]};
            float e0[4], e1[4], e2[4];
#pragma unroll
            for (int q = 0; q < 4; ++q) {
                e0[q] = s_e[n][q][0]; e1[q] = s_e[n][q][1]; e2[q] = s_e[n][q][2];
            }
#pragma unroll
            for (int nt = 0; nt < 4; ++nt) {
                int col = 16 * nt + r16;
                float we0 = ew1f[256 * 64 + col];
                float we1 = ew1f[257 * 64 + col];
                float we2 = ew1f[258 * 64 + col];
                float base = eb1[col] + s_hxi[n * HXP + col];
                float hs = 0.f;
#pragma unroll
                for (int q = 0; q < 4; ++q) {
                    float pre = c[nt][q] + base
                              + e0[q] * we0 + e1[q] * we1 + e2[q] * we2;
                    hs = fmaf(v[q], fmaxf(pre, 0.f), hs);
                }
                s_hs[n * HSP + col] = f2bf(hs);
            }
        }
    }
    __syncthreads();

    // ---------------- E2: agg = (hsum @ W2 + cnt*b2) * invd -> bf16 ---------------
    {
        const int mt  = wv & 1;
        const int nth = (wv >> 1) * 4;
        int n = 16 * mt + r16; if (n > 24) n = 24;
        const ushort* A = s_hs + n * HSP + g * 8;
        f32x4 c[4] = {{0,0,0,0},{0,0,0,0},{0,0,0,0},{0,0,0,0}};
#pragma unroll
        for (int kt = 0; kt < 2; ++kt) {
            short8 a = *reinterpret_cast<const short8*>(A + kt * 32);
#pragma unroll
            for (int nt = 0; nt < 4; ++nt) {
                int col = (nth + nt) * 16 + r16;
                const short8 b = *reinterpret_cast<const short8*>(
                    W + O_W2T + (size_t)col * 64 + kt * 32 + g * 8);
                c[nt] = MFMA16(a, b, c[nt]);
            }
        }
#pragma unroll
        for (int nt = 0; nt < 4; ++nt) {
            int col = (nth + nt) * 16 + r16;
            float b2c = eb2[col];
#pragma unroll
            for (int q = 0; q < 4; ++q) {
                int nr = 16 * mt + 4 * g + q;
                if (nr < 25) {
                    float agg = s_invd[nr] * fmaf(s_cnt[nr], b2c, c[nt][q]);
                    s_ag[nr * XBP + col] = f2bf(agg);
                }
            }
        }
    }
    __syncthreads();

    // ---------------- N1: g1 = relu([x|agg] @ nW1 + nb1) -> bf16 ------------------
    {
        const int mt  = wv & 1;
        const int ntb = (wv >> 1) * 2;
        int n = 16 * mt + r16; if (n > 24) n = 24;
        const ushort* Ax = s_xb + n * XBP + g * 8;
        const ushort* Aa = s_ag + n * XBP + g * 8;
        f32x4 c[2] = {{0,0,0,0},{0,0,0,0}};
#pragma unroll
        for (int kt = 0; kt < 4; ++kt) {
            short8 a = *reinterpret_cast<const short8*>(Ax + kt * 32);
#pragma unroll
            for (int nt = 0; nt < 2; ++nt) {
                int col = (ntb + nt) * 16 + r16;
                const short8 b = *reinterpret_cast<const short8*>(
                    W + O_N1T + (size_t)col * 256 + kt * 32 + g * 8);
                c[nt] = MFMA16(a, b, c[nt]);
            }
        }
#pragma unroll
        for (int kt = 0; kt < 4; ++kt) {
            short8 a = *reinterpret_cast<const short8*>(Aa + kt * 32);
#pragma unroll
            for (int nt = 0; nt < 2; ++nt) {
                int col = (ntb + nt) * 16 + r16;
                const short8 b = *reinterpret_cast<const short8*>(
                    W + O_N1T + (size_t)col * 256 + 128 + kt * 32 + g * 8);
                c[nt] = MFMA16(a, b, c[nt]);
            }
        }
#pragma unroll
        for (int nt = 0; nt < 2; ++nt) {
            int col = (ntb + nt) * 16 + r16;
            float b1c = nb1[col];
#pragma unroll
            for (int q = 0; q < 4; ++q) {
                int nr = 16 * mt + 4 * g + q;
                if (nr < 25)
                    s_g1[nr * HSP + col] = f2bf(fmaxf(c[nt][q] + b1c, 0.f));
            }
        }
    }
    __syncthreads();

    // ---------------- N2: delta = g1 @ nW2 + nb2; fused residual+LN+mask ----------
    {
        const int mt  = wv & 1;
        const int nth = (wv >> 1) * 4;
        int n = 16 * mt + r16; if (n > 24) n = 24;
        const ushort* A = s_g1 + n * HSP + g * 8;
        f32x4 c[4] = {{0,0,0,0},{0,0,0,0},{0,0,0,0},{0,0,0,0}};
#pragma unroll
        for (int kt = 0; kt < 2; ++kt) {
            short8 a = *reinterpret_cast<const short8*>(A + kt * 32);
#pragma unroll
            for (int nt = 0; nt < 4; ++nt) {
                int col = (nth + nt) * 16 + r16;
                const short8 b = *reinterpret_cast<const short8*>(
                    W + O_N2T + (size_t)col * 64 + kt * 32 + g * 8);
                c[nt] = MFMA16(a, b, c[nt]);
            }
        }
        // y = x + has*delta  (x re-read from global, L2-hot)
        float y[4][4];
        const float* xg = emb + (size_t)bt * (NN * DD);
#pragma unroll
        for (int q = 0; q < 4; ++q) {
            int nr = 16 * mt + 4 * g + q;
            int nc = nr < 25 ? nr : 24;
            float hasv = s_has[nc];
#pragma unroll
            for (int nt = 0; nt < 4; ++nt) {
                int col = (nth + nt) * 16 + r16;
                float delta = c[nt][q] + nb2[col];
                y[q][nt] = fmaf(hasv, delta, xg[nc * DD + col]);
            }
        }
        float sm[4], s2[4];
#pragma unroll
        for (int q = 0; q < 4; ++q) {
            float a = (y[q][0] + y[q][1]) + (y[q][2] + y[q][3]);
            float b = fmaf(y[q][0], y[q][0], fmaf(y[q][1], y[q][1],
                      fmaf(y[q][2], y[q][2], y[q][3] * y[q][3])));
#pragma unroll
            for (int o = 1; o < 16; o <<= 1) {
                a += __shfl_xor(a, o);
                b += __shfl_xor(b, o);
            }
            sm[q] = a; s2[q] = b;
        }
        if (r16 == 0) {
#pragma unroll
            for (int q = 0; q < 4; ++q) {
                int nr = 16 * mt + 4 * g + q;
                if (nr < 25) {
                    s_red[nr][wv >> 1][0] = sm[q];
                    s_red[nr][wv >> 1][1] = s2[q];
                }
            }
        }
        __syncthreads();
#pragma unroll
        for (int q = 0; q < 4; ++q) {
            int nr = 16 * mt + 4 * g + q;
            if (nr < 25) {
                float S   = s_red[nr][0][0] + s_red[nr][1][0];
                float S2  = s_red[nr][0][1] + s_red[nr][1][1];
                float mu  = S * (1.0f / 128.0f);
                float var = S2 * (1.0f / 128.0f) - mu * mu;
                float rs  = rsqrtf(var + 1e-5f);
                float mk  = s_m[nr] ? 1.f : 0.f;
                float* op = out + (size_t)bt * (NN * DD) + nr * DD;
#pragma unroll
                for (int nt = 0; nt < 4; ++nt) {
                    int col = (nth + nt) * 16 + r16;
                    op[col] = fmaf((y[q][nt] - mu) * rs, lng[col], lnb[col]) * mk;
                }
            }
        }
    }
}

extern "C" void kernel_launch(void* const* d_in, const int* in_sizes, int n_in,
                              void* d_out, int out_size, void* d_ws, size_t ws_size,
                              hipStream_t stream) {
    const float* emb    = (const float*)d_in[0];
    const float* bboxes = (const float*)d_in[1];
    const int*   pmask  = (const int*)  d_in[2];
    const float* ew1    = (const float*)d_in[3];
    const float* eb1    = (const float*)d_in[4];
    const float* ew2    = (const float*)d_in[5];
    const float* eb2    = (const float*)d_in[6];
    const float* nw1    = (const float*)d_in[7];
    const float* nb1    = (const float*)d_in[8];
    const float* nw2    = (const float*)d_in[9];
    const float* nb2    = (const float*)d_in[10];
    const float* lng    = (const float*)d_in[11];
    const float* lnb    = (const float*)d_in[12];
    float* out = (float*)d_out;
    ushort* W  = (ushort*)d_ws;

    prep_kernel<<<64, 256, 0, stream>>>(ew1, ew2, nw1, nw2, W);

    const int BT = in_sizes[2] / NN;   // 2048 frames
    ig4_kernel<<<BT, 256, 0, stream>>>(
        emb, bboxes, pmask, ew1, eb1, eb2, nb1, nb2, lng, lnb, W, out);
}